// Round 7
// baseline (97.056 us; speedup 1.0000x reference)
//
#include <hip/hip_runtime.h>
#include <hip/hip_bf16.h>

// SparseConv1x1 as a dense bf16 MFMA GEMM: out[256, 25088] = W[256,256] * X[256, 25088]
// W is 10% dense -> densify to bf16 (128 KB) in d_ws, pre-swizzled into
// v_mfma_f32_32x32x16_bf16 A-operand fragment order.
//
// Layouts (CDNA4 32x32x16, C/D verified learn_hip m74/m101):
//   A[m][k]: lane = (m&31) + 32*((k>>3)&1), halfword j = k&7
//   B[k][n]: lane = (n&31) + 32*((k>>3)&1), halfword j = k&7
//   C/D    : col n = lane&31, row m = (reg&3) + 8*(reg>>2) + 4*(lane>>5)
//
// R7 vs R6:
//  - Epilogue stores back to NORMAL (L2 write-back) — nt stores were the R6
//    regression suspect (streamed 128B chunks bypassing L2 aggregation).
//  - Staging fp32->bf16 uses packed __float22bfloat162_rn (v_cvt_pk_bf16_f32):
//    1 VALU per 2 elements instead of ~7 — ~4x staging-VALU cut.
//  - Keep nt loads (X single-touch; keeps 784x-reread W L2-resident) and the
//    single w_build prep kernel (no memset, covers all 65536 entries).

#define HW    3136
#define CH    256
#define NF    256
#define NT    32            // pixels per tile
#define NTILE 98            // HW / NT

typedef __attribute__((ext_vector_type(8)))  short bf16x8;
typedef __attribute__((ext_vector_type(16))) float f32x16;

__device__ __forceinline__ unsigned rne_bf16(float f) {
    unsigned u = __float_as_uint(f);
    return (u + 0x7FFFu + ((u >> 16) & 1u)) >> 16;   // RNE to bf16, low 16 bits
}

__device__ __forceinline__ int pk2_bf16(float lo, float hi) {
    __hip_bfloat162 h = __float22bfloat162_rn(make_float2(lo, hi));  // packed cvt
    union { __hip_bfloat162 h2; int i; } u;
    u.h2 = h;
    return u.i;                        // lo in bits [15:0], hi in [31:16]
}

// Build the full swizzled dense bf16 W: block = row m, thread = col c.
// Covers every entry -> no prior memset required.
__global__ __launch_bounds__(256) void w_build(
    const float* __restrict__ values,
    const int*   __restrict__ row_ids,
    const int*   __restrict__ col_ids,
    unsigned short* __restrict__ wsw,   // 128 chunks * 512 halfwords
    int nnz)
{
    const int m = blockIdx.x;
    const int t = threadIdx.x;

    __shared__ int   scol[256];
    __shared__ float sval[256];
    __shared__ int   sb[2];

    if (t < 2) {                        // lower_bound(row_ids, m) and (m+1)
        const int target = m + t;
        int lo = 0, hi = nnz;
        while (lo < hi) { int md = (lo + hi) >> 1; if (row_ids[md] < target) lo = md + 1; else hi = md; }
        sb[t] = lo;
    }
    __syncthreads();
    const int s = sb[0];
    const int L = sb[1] - s;            // row length (<= 256)
    if (t < L) { scol[t] = col_ids[s + t]; sval[t] = values[s + t]; }
    __syncthreads();

    float v = 0.f;                      // broadcast LDS scan (~26 iters, same addr -> free)
    for (int i = 0; i < L; ++i) if (scol[i] == t) v = sval[i];

    const int chunk = (m >> 5) * 16 + (t >> 4);
    const int lane  = (m & 31) + 32 * ((t >> 3) & 1);
    wsw[chunk * 512 + lane * 8 + (t & 7)] = (unsigned short)rne_bf16(v);
}

__global__ __launch_bounds__(256) void spmm_mfma(
    const float*  __restrict__ X,      // [8][256][3136]
    const bf16x8* __restrict__ wsw,    // swizzled W, [(mt*16+kt)*64 + lane]
    float*        __restrict__ out)    // [8][256][3136]
{
    __shared__ int4 ldsq[16 * 64];     // 16 KB: chunk kt, lane -> 8 bf16 of B-frag

    const int t  = threadIdx.x;
    const int l  = t & 63;
    const int w  = t >> 6;
    const int n0 = blockIdx.x * NT;
    const int b  = blockIdx.y;

    const float* __restrict__ Xb = X + (size_t)b * (CH * HW);

    // ---- Stage X tile into LDS in B-fragment order (nt loads: X read once) ----
    #pragma unroll
    for (int i = 0; i < 4; ++i) {
        const int kt    = i * 4 + w;
        const int kbase = kt * 16 + (l >> 5) * 8;
        const float* __restrict__ p = Xb + (size_t)kbase * HW + n0 + (l & 31);
        const float r0 = __builtin_nontemporal_load(p + 0 * HW);
        const float r1 = __builtin_nontemporal_load(p + 1 * HW);
        const float r2 = __builtin_nontemporal_load(p + 2 * HW);
        const float r3 = __builtin_nontemporal_load(p + 3 * HW);
        const float r4 = __builtin_nontemporal_load(p + 4 * HW);
        const float r5 = __builtin_nontemporal_load(p + 5 * HW);
        const float r6 = __builtin_nontemporal_load(p + 6 * HW);
        const float r7 = __builtin_nontemporal_load(p + 7 * HW);
        int4 v;
        v.x = pk2_bf16(r0, r1);
        v.y = pk2_bf16(r2, r3);
        v.z = pk2_bf16(r4, r5);
        v.w = pk2_bf16(r6, r7);
        ldsq[kt * 64 + l] = v;          // lane-contiguous 16B: conflict-free
    }
    __syncthreads();

    // ---- MFMA: wave w owns rows w*64 .. w*64+63 (m-tiles 2w, 2w+1) ----
    const bf16x8* __restrict__ ldsv = (const bf16x8*)ldsq;
    const int mt0 = w * 2, mt1 = w * 2 + 1;

    f32x16 acc0, acc1;
    #pragma unroll
    for (int i = 0; i < 16; ++i) { acc0[i] = 0.f; acc1[i] = 0.f; }

    #pragma unroll
    for (int kt = 0; kt < 16; ++kt) {
        const bf16x8 bfrag = ldsv[kt * 64 + l];
        const bf16x8 a0 = wsw[(mt0 * 16 + kt) * 64 + l];
        const bf16x8 a1 = wsw[(mt1 * 16 + kt) * 64 + l];
        acc0 = __builtin_amdgcn_mfma_f32_32x32x16_bf16(a0, bfrag, acc0, 0, 0, 0);
        acc1 = __builtin_amdgcn_mfma_f32_32x32x16_bf16(a1, bfrag, acc1, 0, 0, 0);
    }

    // ---- Epilogue: normal stores (L2 write-back) ----
    float* __restrict__ ob = out + (size_t)b * (NF * HW) + n0 + (l & 31);
    const int rbase0 = w * 64;
    const int rbase1 = w * 64 + 32;
    const int rl     = 4 * (l >> 5);
    #pragma unroll
    for (int i = 0; i < 16; ++i) {
        const int row = (i & 3) + 8 * (i >> 2) + rl;
        ob[(size_t)(rbase0 + row) * HW] = acc0[i];
        ob[(size_t)(rbase1 + row) * HW] = acc1[i];
    }
}

extern "C" void kernel_launch(void* const* d_in, const int* in_sizes, int n_in,
                              void* d_out, int out_size, void* d_ws, size_t ws_size,
                              hipStream_t stream) {
    const float* inputs  = (const float*)d_in[0];
    const float* values  = (const float*)d_in[1];
    const int*   row_ids = (const int*)  d_in[2];
    const int*   col_ids = (const int*)  d_in[3];
    const int nnz = in_sizes[1];

    unsigned short* wsw = (unsigned short*)d_ws;   // 128 KB swizzled dense bf16 W

    w_build<<<NF, dim3(256, 1, 1), 0, stream>>>(values, row_ids, col_ids, wsw, nnz);

    dim3 grid(NTILE, 8, 1);
    spmm_mfma<<<grid, dim3(256, 1, 1), 0, stream>>>(
        inputs, (const bf16x8*)d_ws, (float*)d_out);
}

// Round 8
// 93.372 us; speedup vs baseline: 1.0395x; 1.0395x over previous
//
#include <hip/hip_runtime.h>

// SparseConv1x1 as a dense bf16 MFMA GEMM: out[256, 25088] = W[256,256] * X[256, 25088]
// W is 10% dense -> densify to bf16 (128 KB) in d_ws, pre-swizzled into
// v_mfma_f32_32x32x16_bf16 A-operand fragment order.
//
// Layouts (CDNA4 32x32x16, C/D verified learn_hip m74/m101):
//   A[m][k]: lane = (m&31) + 32*((k>>3)&1), halfword j = k&7
//   B[k][n]: lane = (n&31) + 32*((k>>3)&1), halfword j = k&7
//   C/D    : col n = lane&31, row m = (reg&3) + 8*(reg>>2) + 4*(lane>>5)
//
// R8 = R5's spmm (best measured: plain cached loads/stores, manual integer
// rne_bf16) + R6's w_build prep (single dispatch, no memset).
// R6/R7 regressions traced to nt-load hints and __float22bfloat162_rn lowering.

#define HW    3136
#define CH    256
#define NF    256
#define NT    32            // pixels per tile
#define NTILE 98            // HW / NT

typedef __attribute__((ext_vector_type(8)))  short bf16x8;
typedef __attribute__((ext_vector_type(16))) float f32x16;

__device__ __forceinline__ unsigned rne_bf16(float f) {
    unsigned u = __float_as_uint(f);
    return (u + 0x7FFFu + ((u >> 16) & 1u)) >> 16;   // RNE to bf16, low 16 bits
}

// Build the full swizzled dense bf16 W: block = row m, thread = col c.
// Covers every entry -> no prior memset required.
__global__ __launch_bounds__(256) void w_build(
    const float* __restrict__ values,
    const int*   __restrict__ row_ids,
    const int*   __restrict__ col_ids,
    unsigned short* __restrict__ wsw,   // 128 chunks * 512 halfwords
    int nnz)
{
    const int m = blockIdx.x;
    const int t = threadIdx.x;

    __shared__ int   scol[256];
    __shared__ float sval[256];
    __shared__ int   sb[2];

    if (t < 2) {                        // lower_bound(row_ids, m) and (m+1)
        const int target = m + t;
        int lo = 0, hi = nnz;
        while (lo < hi) { int md = (lo + hi) >> 1; if (row_ids[md] < target) lo = md + 1; else hi = md; }
        sb[t] = lo;
    }
    __syncthreads();
    const int s = sb[0];
    const int L = sb[1] - s;            // row length (<= 256)
    if (t < L) { scol[t] = col_ids[s + t]; sval[t] = values[s + t]; }
    __syncthreads();

    float v = 0.f;                      // broadcast LDS scan (~26 iters, same addr -> free)
    for (int i = 0; i < L; ++i) if (scol[i] == t) v = sval[i];

    const int chunk = (m >> 5) * 16 + (t >> 4);
    const int lane  = (m & 31) + 32 * ((t >> 3) & 1);
    wsw[chunk * 512 + lane * 8 + (t & 7)] = (unsigned short)rne_bf16(v);
}

__global__ __launch_bounds__(256) void spmm_mfma(
    const float*  __restrict__ X,      // [8][256][3136]
    const bf16x8* __restrict__ wsw,    // swizzled W, [(mt*16+kt)*64 + lane]
    float*        __restrict__ out)    // [8][256][3136]
{
    __shared__ int4 ldsq[16 * 64];     // 16 KB: chunk kt, lane -> 8 bf16 of B-frag

    const int t  = threadIdx.x;
    const int l  = t & 63;
    const int w  = t >> 6;
    const int n0 = blockIdx.x * NT;
    const int b  = blockIdx.y;

    const float* __restrict__ Xb = X + (size_t)b * (CH * HW);

    // ---- Stage X tile into LDS in B-fragment order ----
    // Slot (kt, lane): k = kt*16 + (l>>5)*8 + j (j=0..7), n = n0 + (l&31).
    // Thread t fills 4 slots: kt = i*4 + (t>>6).
    #pragma unroll
    for (int i = 0; i < 4; ++i) {
        const int kt    = i * 4 + w;
        const int kbase = kt * 16 + (l >> 5) * 8;
        const float* __restrict__ p = Xb + (size_t)kbase * HW + n0 + (l & 31);
        unsigned r0 = rne_bf16(p[0 * HW]);
        unsigned r1 = rne_bf16(p[1 * HW]);
        unsigned r2 = rne_bf16(p[2 * HW]);
        unsigned r3 = rne_bf16(p[3 * HW]);
        unsigned r4 = rne_bf16(p[4 * HW]);
        unsigned r5 = rne_bf16(p[5 * HW]);
        unsigned r6 = rne_bf16(p[6 * HW]);
        unsigned r7 = rne_bf16(p[7 * HW]);
        int4 v;
        v.x = (int)(r0 | (r1 << 16));
        v.y = (int)(r2 | (r3 << 16));
        v.z = (int)(r4 | (r5 << 16));
        v.w = (int)(r6 | (r7 << 16));
        ldsq[kt * 64 + l] = v;          // lane-contiguous 16B: conflict-free
    }
    __syncthreads();

    // ---- MFMA: wave w owns rows w*64 .. w*64+63 (m-tiles 2w, 2w+1) ----
    const bf16x8* __restrict__ ldsv = (const bf16x8*)ldsq;
    const int mt0 = w * 2, mt1 = w * 2 + 1;

    f32x16 acc0, acc1;
    #pragma unroll
    for (int i = 0; i < 16; ++i) { acc0[i] = 0.f; acc1[i] = 0.f; }

    #pragma unroll
    for (int kt = 0; kt < 16; ++kt) {
        const bf16x8 bfrag = ldsv[kt * 64 + l];
        const bf16x8 a0 = wsw[(mt0 * 16 + kt) * 64 + l];
        const bf16x8 a1 = wsw[(mt1 * 16 + kt) * 64 + l];
        acc0 = __builtin_amdgcn_mfma_f32_32x32x16_bf16(a0, bfrag, acc0, 0, 0, 0);
        acc1 = __builtin_amdgcn_mfma_f32_32x32x16_bf16(a1, bfrag, acc1, 0, 0, 0);
    }

    // ---- Epilogue: C/D col = n0 + (l&31), row = (i&3) + 8*(i>>2) + 4*(l>>5) ----
    float* __restrict__ ob = out + (size_t)b * (NF * HW) + n0 + (l & 31);
    const int rbase0 = w * 64;
    const int rbase1 = w * 64 + 32;
    const int rl     = 4 * (l >> 5);
    #pragma unroll
    for (int i = 0; i < 16; ++i) {
        const int row = (i & 3) + 8 * (i >> 2) + rl;
        ob[(size_t)(rbase0 + row) * HW] = acc0[i];
        ob[(size_t)(rbase1 + row) * HW] = acc1[i];
    }
}

extern "C" void kernel_launch(void* const* d_in, const int* in_sizes, int n_in,
                              void* d_out, int out_size, void* d_ws, size_t ws_size,
                              hipStream_t stream) {
    const float* inputs  = (const float*)d_in[0];
    const float* values  = (const float*)d_in[1];
    const int*   row_ids = (const int*)  d_in[2];
    const int*   col_ids = (const int*)  d_in[3];
    const int nnz = in_sizes[1];

    unsigned short* wsw = (unsigned short*)d_ws;   // 128 KB swizzled dense bf16 W

    w_build<<<NF, dim3(256, 1, 1), 0, stream>>>(values, row_ids, col_ids, wsw, nnz);

    dim3 grid(NTILE, 8, 1);
    spmm_mfma<<<grid, dim3(256, 1, 1), 0, stream>>>(
        inputs, (const bf16x8*)d_ws, (float*)d_out);
}

// Round 9
// 88.728 us; speedup vs baseline: 1.0939x; 1.0523x over previous
//
#include <hip/hip_runtime.h>

// SparseConv1x1 as a dense bf16 MFMA GEMM: out[256, 25088] = W[256,256] * X[256, 25088]
// W is 10% dense -> densify to bf16 (128 KB) in d_ws, pre-swizzled into
// v_mfma_f32_32x32x16_bf16 A-operand fragment order.
//
// Layouts (CDNA4 32x32x16, C/D verified learn_hip m74/m101):
//   A[m][k]: lane = (m&31) + 32*((k>>3)&1), halfword j = k&7
//   B[k][n]: lane = (n&31) + 32*((k>>3)&1), halfword j = k&7
//   C/D    : col n = lane&31, row m = (reg&3) + 8*(reg>>2) + 4*(lane>>5)
//
// R9 = exact R5 (best measured: 89.3 us): memset + flat scatter prep, plain
// cached loads/stores, manual integer rne_bf16. R6-R8 A/B showed w_build,
// nt-hints, and __float22bfloat162_rn each neutral-to-negative.

#define HW    3136
#define CH    256
#define NF    256
#define NT    32            // pixels per tile
#define NTILE 98            // HW / NT

typedef __attribute__((ext_vector_type(8)))  short bf16x8;
typedef __attribute__((ext_vector_type(16))) float f32x16;

__device__ __forceinline__ unsigned rne_bf16(float f) {
    unsigned u = __float_as_uint(f);
    return (u + 0x7FFFu + ((u >> 16) & 1u)) >> 16;   // RNE to bf16, low 16 bits
}

// Scatter CSR nonzeros into the swizzled dense bf16 W (zeroed beforehand).
__global__ __launch_bounds__(256) void w_scatter(
    const float* __restrict__ values,
    const int*   __restrict__ row_ids,
    const int*   __restrict__ col_ids,
    unsigned short* __restrict__ wsw,   // 128 chunks * 512 halfwords
    int nnz)
{
    int i = blockIdx.x * 256 + threadIdx.x;
    if (i >= nnz) return;
    const int m = row_ids[i];
    const int c = col_ids[i];
    const int chunk = (m >> 5) * 16 + (c >> 4);
    const int lane  = (m & 31) + 32 * ((c >> 3) & 1);
    wsw[chunk * 512 + lane * 8 + (c & 7)] = (unsigned short)rne_bf16(values[i]);
}

__global__ __launch_bounds__(256) void spmm_mfma(
    const float*  __restrict__ X,      // [8][256][3136]
    const bf16x8* __restrict__ wsw,    // swizzled W, [(mt*16+kt)*64 + lane]
    float*        __restrict__ out)    // [8][256][3136]
{
    __shared__ int4 ldsq[16 * 64];     // 16 KB: chunk kt, lane -> 8 bf16 of B-frag

    const int t  = threadIdx.x;
    const int l  = t & 63;
    const int w  = t >> 6;
    const int n0 = blockIdx.x * NT;
    const int b  = blockIdx.y;

    const float* __restrict__ Xb = X + (size_t)b * (CH * HW);

    // ---- Stage X tile into LDS in B-fragment order ----
    // Slot (kt, lane): k = kt*16 + (l>>5)*8 + j (j=0..7), n = n0 + (l&31).
    // Thread t fills 4 slots: kt = i*4 + (t>>6).
    #pragma unroll
    for (int i = 0; i < 4; ++i) {
        const int kt    = i * 4 + w;
        const int kbase = kt * 16 + (l >> 5) * 8;
        const float* __restrict__ p = Xb + (size_t)kbase * HW + n0 + (l & 31);
        unsigned r0 = rne_bf16(p[0 * HW]);
        unsigned r1 = rne_bf16(p[1 * HW]);
        unsigned r2 = rne_bf16(p[2 * HW]);
        unsigned r3 = rne_bf16(p[3 * HW]);
        unsigned r4 = rne_bf16(p[4 * HW]);
        unsigned r5 = rne_bf16(p[5 * HW]);
        unsigned r6 = rne_bf16(p[6 * HW]);
        unsigned r7 = rne_bf16(p[7 * HW]);
        int4 v;
        v.x = (int)(r0 | (r1 << 16));
        v.y = (int)(r2 | (r3 << 16));
        v.z = (int)(r4 | (r5 << 16));
        v.w = (int)(r6 | (r7 << 16));
        ldsq[kt * 64 + l] = v;          // lane-contiguous 16B: conflict-free
    }
    __syncthreads();

    // ---- MFMA: wave w owns rows w*64 .. w*64+63 (m-tiles 2w, 2w+1) ----
    const bf16x8* __restrict__ ldsv = (const bf16x8*)ldsq;
    const int mt0 = w * 2, mt1 = w * 2 + 1;

    f32x16 acc0, acc1;
    #pragma unroll
    for (int i = 0; i < 16; ++i) { acc0[i] = 0.f; acc1[i] = 0.f; }

    #pragma unroll
    for (int kt = 0; kt < 16; ++kt) {
        const bf16x8 bfrag = ldsv[kt * 64 + l];
        const bf16x8 a0 = wsw[(mt0 * 16 + kt) * 64 + l];
        const bf16x8 a1 = wsw[(mt1 * 16 + kt) * 64 + l];
        acc0 = __builtin_amdgcn_mfma_f32_32x32x16_bf16(a0, bfrag, acc0, 0, 0, 0);
        acc1 = __builtin_amdgcn_mfma_f32_32x32x16_bf16(a1, bfrag, acc1, 0, 0, 0);
    }

    // ---- Epilogue: C/D col = n0 + (l&31), row = (i&3) + 8*(i>>2) + 4*(l>>5) ----
    float* __restrict__ ob = out + (size_t)b * (NF * HW) + n0 + (l & 31);
    const int rbase0 = w * 64;
    const int rbase1 = w * 64 + 32;
    const int rl     = 4 * (l >> 5);
    #pragma unroll
    for (int i = 0; i < 16; ++i) {
        const int row = (i & 3) + 8 * (i >> 2) + rl;
        ob[(size_t)(rbase0 + row) * HW] = acc0[i];
        ob[(size_t)(rbase1 + row) * HW] = acc1[i];
    }
}

extern "C" void kernel_launch(void* const* d_in, const int* in_sizes, int n_in,
                              void* d_out, int out_size, void* d_ws, size_t ws_size,
                              hipStream_t stream) {
    const float* inputs  = (const float*)d_in[0];
    const float* values  = (const float*)d_in[1];
    const int*   row_ids = (const int*)  d_in[2];
    const int*   col_ids = (const int*)  d_in[3];
    const int nnz = in_sizes[1];

    unsigned short* wsw = (unsigned short*)d_ws;   // 128 KB swizzled dense bf16 W

    hipMemsetAsync(d_ws, 0, 128 * 1024, stream);
    w_scatter<<<(nnz + 255) / 256, dim3(256, 1, 1), 0, stream>>>(
        values, row_ids, col_ids, wsw, nnz);

    dim3 grid(NTILE, 8, 1);
    spmm_mfma<<<grid, dim3(256, 1, 1), 0, stream>>>(
        inputs, (const bf16x8*)d_ws, (float*)d_out);
}